// Round 3
// baseline (235.777 us; speedup 1.0000x reference)
//
#include <hip/hip_runtime.h>
#include <hip/hip_bf16.h>

typedef __attribute__((ext_vector_type(8))) short bf16x8;
typedef __attribute__((ext_vector_type(4))) float f32x4;
typedef __attribute__((ext_vector_type(16))) float f32x16;
typedef __attribute__((ext_vector_type(8))) unsigned short ushort8v;
typedef __attribute__((ext_vector_type(4))) unsigned short ushort4v;

#define MFMA16(a, b, c) __builtin_amdgcn_mfma_f32_16x16x32_bf16((a), (b), (c), 0, 0, 0)
#define MFMA32(a, b, c) __builtin_amdgcn_mfma_f32_32x32x16_bf16((a), (b), (c), 0, 0, 0)

__device__ __forceinline__ unsigned short f2bf(float f) {
  union { float f; unsigned int u; } v; v.f = f;
  unsigned int r = v.u + 0x7FFFu + ((v.u >> 16) & 1u);
  return (unsigned short)(r >> 16);
}

// packed f32 pair -> bf16 pair (lo = a, hi = b), RNE via hip_bf16 API
__device__ __forceinline__ unsigned int pkbf(float a, float b) {
  float2 t; t.x = a; t.y = b;
  __hip_bfloat162 h = __float22bfloat162_rn(t);
  union { __hip_bfloat162 h; unsigned int w; } c; c.h = h;
  return c.w;
}

// ---------------- transpose + cast: in (R,C) f32 -> out (C,R) bf16, batched ----------------
__global__ __launch_bounds__(256) void transpose_cast_kernel(
    const float* __restrict__ in, unsigned short* __restrict__ out, int R, int C) {
  __shared__ float tile[32][33];
  int c0 = blockIdx.x * 32, r0 = blockIdx.y * 32, b = blockIdx.z;
  const float* inb = in + (size_t)b * R * C;
  unsigned short* outb = out + (size_t)b * R * C;
  int tx = threadIdx.x & 31, ty = threadIdx.x >> 5;
#pragma unroll
  for (int k = 0; k < 4; ++k)
    tile[ty + 8 * k][tx] = inb[(size_t)(r0 + ty + 8 * k) * C + c0 + tx];
  __syncthreads();
#pragma unroll
  for (int k = 0; k < 4; ++k)
    outb[(size_t)(c0 + ty + 8 * k) * R + r0 + tx] = f2bf(tile[tx][ty + 8 * k]);
}

// ---------------- shared NT-GEMM core ----------------
__device__ __forceinline__ void gemm_acc(
    const unsigned short* __restrict__ A, const unsigned short* __restrict__ Bt,
    int l0, int o0, f32x4 acc[4][2],
    unsigned short (*As)[80], unsigned short (*Bs)[80]) {
  int tid = threadIdx.x, lane = tid & 63, wave = tid >> 6;
  int wl = wave >> 1, wo = wave & 1, lg = lane >> 4, lr = lane & 15;
  for (int kb = 0; kb < 512; kb += 64) {
    {
      int row = tid >> 1, cc = (tid & 1) * 32;
      const ushort8v* src = (const ushort8v*)(A + (size_t)(l0 + row) * 512 + kb + cc);
#pragma unroll
      for (int i = 0; i < 4; ++i) *(ushort8v*)&As[row][cc + 8 * i] = src[i];
      int row2 = tid >> 2, c2 = (tid & 3) * 16;
      const ushort8v* srcb = (const ushort8v*)(Bt + (size_t)(o0 + row2) * 512 + kb + c2);
      *(ushort8v*)&Bs[row2][c2] = srcb[0];
      *(ushort8v*)&Bs[row2][c2 + 8] = srcb[1];
    }
    __syncthreads();
#pragma unroll
    for (int kc = 0; kc < 2; ++kc) {
      bf16x8 af[4], bfr[2];
#pragma unroll
      for (int mf = 0; mf < 4; ++mf)
        af[mf] = *(const bf16x8*)&As[wl * 64 + mf * 16 + lr][kc * 32 + 8 * lg];
#pragma unroll
      for (int nf = 0; nf < 2; ++nf)
        bfr[nf] = *(const bf16x8*)&Bs[wo * 32 + nf * 16 + lr][kc * 32 + 8 * lg];
#pragma unroll
      for (int mf = 0; mf < 4; ++mf)
#pragma unroll
        for (int nf = 0; nf < 2; ++nf)
          acc[mf][nf] = MFMA16(af[mf], bfr[nf], acc[mf][nf]);
    }
    __syncthreads();
  }
}

// Q projection: C (8192, 512) bf16, PRE-SCALED by dim_head^-0.5 * log2(e).
__global__ __launch_bounds__(256) void gemm_q_kernel(
    const unsigned short* __restrict__ A, const unsigned short* __restrict__ Bt,
    unsigned short* __restrict__ C) {
  __shared__ unsigned short As[128][80];
  __shared__ unsigned short Bs[64][80];
  f32x4 acc[4][2] = {};
  int l0 = blockIdx.x * 128, o0 = blockIdx.y * 64;
  gemm_acc(A, Bt, l0, o0, acc, As, Bs);
  int lane = threadIdx.x & 63, wave = threadIdx.x >> 6;
  int wl = wave >> 1, wo = wave & 1, lg = lane >> 4, lr = lane & 15;
  const float qs = 0.18033688011112042f;  // 0.125 * log2(e)
#pragma unroll
  for (int mf = 0; mf < 4; ++mf)
#pragma unroll
    for (int nf = 0; nf < 2; ++nf)
#pragma unroll
      for (int r = 0; r < 4; ++r) {
        int row = l0 + wl * 64 + mf * 16 + 4 * lg + r;
        int col = o0 + wo * 32 + nf * 16 + lr;
        C[(size_t)row * 512 + col] = f2bf(acc[mf][nf][r] * qs);
      }
}

// KV projection: cols [0,512) -> K (B*M, 512); cols [512,1024) -> Vt (B,H,64,M).
__global__ __launch_bounds__(256) void gemm_kv_kernel(
    const unsigned short* __restrict__ A, const unsigned short* __restrict__ Bt,
    unsigned short* __restrict__ K, unsigned short* __restrict__ Vt) {
  __shared__ unsigned short As[128][80];
  __shared__ unsigned short Bs[64][80];
  f32x4 acc[4][2] = {};
  int l0 = blockIdx.x * 128, o0 = blockIdx.y * 64;
  gemm_acc(A, Bt, l0, o0, acc, As, Bs);
  int lane = threadIdx.x & 63, wave = threadIdx.x >> 6;
  int wl = wave >> 1, wo = wave & 1, lg = lane >> 4, lr = lane & 15;
  if (o0 < 512) {
#pragma unroll
    for (int mf = 0; mf < 4; ++mf)
#pragma unroll
      for (int nf = 0; nf < 2; ++nf)
#pragma unroll
        for (int r = 0; r < 4; ++r) {
          int row = l0 + wl * 64 + mf * 16 + 4 * lg + r;
          int col = o0 + wo * 32 + nf * 16 + lr;
          K[(size_t)row * 512 + col] = f2bf(acc[mf][nf][r]);
        }
  } else {
    int b = l0 >> 11;
#pragma unroll
    for (int mf = 0; mf < 4; ++mf)
#pragma unroll
      for (int nf = 0; nf < 2; ++nf) {
        int m0 = (l0 & 2047) + wl * 64 + mf * 16 + 4 * lg;
        int oh = (o0 - 512) + wo * 32 + nf * 16 + lr;
        int h = oh >> 6, d = oh & 63;
        ushort4v pk;
#pragma unroll
        for (int r = 0; r < 4; ++r) pk[r] = f2bf(acc[mf][nf][r]);
        *(ushort4v*)&Vt[(size_t)((b * 8 + h) * 64 + d) * 2048 + m0] = pk;
      }
  }
}

// Out projection: out (B, 512, N) fp32 transposed store + bias.
__global__ __launch_bounds__(256) void gemm_out_kernel(
    const unsigned short* __restrict__ A, const unsigned short* __restrict__ Bt,
    float* __restrict__ Out, const float* __restrict__ bias) {
  __shared__ unsigned short As[128][80];
  __shared__ unsigned short Bs[64][80];
  f32x4 acc[4][2] = {};
  int l0 = blockIdx.x * 128, o0 = blockIdx.y * 64;
  gemm_acc(A, Bt, l0, o0, acc, As, Bs);
  int lane = threadIdx.x & 63, wave = threadIdx.x >> 6;
  int wl = wave >> 1, wo = wave & 1, lg = lane >> 4, lr = lane & 15;
#pragma unroll
  for (int mf = 0; mf < 4; ++mf)
#pragma unroll
    for (int nf = 0; nf < 2; ++nf) {
      int row = l0 + wl * 64 + mf * 16 + 4 * lg;
      int col = o0 + wo * 32 + nf * 16 + lr;
      int b = row >> 11, n = row & 2047;
      float bv = bias[col];
      f32x4 v = acc[mf][nf];
#pragma unroll
      for (int r = 0; r < 4; ++r) v[r] += bv;
      *(f32x4*)&Out[((size_t)(b * 512 + col)) * 2048 + n] = v;
    }
}

// ---------------- flash attention, swapped-QK^T, zero-LDS, permutation-robust ----------------
// grid (16, 8, 4); 4 independent waves x 32 q-rows; KV tile 64; D = 64.
// S^T = mfma32(K, Q): both operands from memory with identical assumed k-maps -> robust.
// Verified C/D layout: lane owns q = lane&31; s[r] = S^T[kv=(r&3)+8*(r>>2)+4*hi][q].
// PV uses a CHOSEN k-map equal to the kv-set each lane owns:
//   slot (hi, j) <-> kv = 16*t + (j&3) + 8*(j>>2) + 4*hi
// so P-frag = pack of 8 consecutive s-regs (no cross-lane), V-frag loaded with same map.
__global__ __launch_bounds__(256) void attn_kernel(
    const unsigned short* __restrict__ Qb, const unsigned short* __restrict__ Kb,
    const unsigned short* __restrict__ Vt, unsigned short* __restrict__ Ob) {
  int h = blockIdx.y, b = blockIdx.z;
  int tid = threadIdx.x, wave = tid >> 6, lane = tid & 63;
  int l31 = lane & 31, hi = lane >> 5;
  int qrow = b * 2048 + blockIdx.x * 128 + wave * 32 + l31;

  const unsigned short* qp = Qb + (size_t)qrow * 512 + h * 64 + 8 * hi;
  bf16x8 qf[4];
#pragma unroll
  for (int dk = 0; dk < 4; ++dk) qf[dk] = *(const bf16x8*)(qp + 16 * dk);

  const unsigned short* kbase = Kb + ((size_t)(b * 2048 + l31)) * 512 + h * 64 + 8 * hi;
  // vbase points at Vt row dv=l31, column offset 4*hi (the lane's kv-slot base)
  const unsigned short* vbase = Vt + ((size_t)((b * 8 + h) * 64 + l31)) * 2048 + 4 * hi;

  f32x16 o0 = {}, o1 = {};
  float m_run = -1e30f, lsum = 0.0f;

  // prologue: K frags for tile 0 (A-operand rows kv = ksub*32 + l31)
  bf16x8 kf[8];
#pragma unroll
  for (int dk = 0; dk < 4; ++dk) {
    kf[dk] = *(const bf16x8*)(kbase + dk * 16);
    kf[4 + dk] = *(const bf16x8*)(kbase + 32 * 512 + dk * 16);
  }

#pragma unroll 1
  for (int m0 = 0; m0 < 2048; m0 += 64) {
    // S^T for two 32-kv subtiles
    f32x16 s0 = {}, s1 = {};
#pragma unroll
    for (int dk = 0; dk < 4; ++dk) s0 = MFMA32(kf[dk], qf[dk], s0);
#pragma unroll
    for (int dk = 0; dk < 4; ++dk) s1 = MFMA32(kf[4 + dk], qf[dk], s1);

    // V fragment loads for current tile, chosen k-map:
    // vw[t][0]: V[kv=16t+4hi+0..3][dv=l31], vw[t][1]: V[kv=16t+8+4hi+0..3][dv=l31]
    // vw[t][2..3]: same for dv = 32 + l31
    ushort4v vw[4][4];
#pragma unroll
    for (int t = 0; t < 4; ++t) {
      vw[t][0] = *(const ushort4v*)(vbase + m0 + 16 * t);
      vw[t][1] = *(const ushort4v*)(vbase + m0 + 16 * t + 8);
      vw[t][2] = *(const ushort4v*)(vbase + (size_t)32 * 2048 + m0 + 16 * t);
      vw[t][3] = *(const ushort4v*)(vbase + (size_t)32 * 2048 + m0 + 16 * t + 8);
    }

    // K prefetch for next tile (latency hidden under softmax VALU)
    {
      int mn = (m0 + 64) & 2047;
#pragma unroll
      for (int dk = 0; dk < 4; ++dk) {
        kf[dk] = *(const bf16x8*)(kbase + (size_t)mn * 512 + dk * 16);
        kf[4 + dk] = *(const bf16x8*)(kbase + (size_t)(mn + 32) * 512 + dk * 16);
      }
    }

    // row max over this lane's 32 scores (tree), then partner (lane^32) combine
    float t8[8];
#pragma unroll
    for (int i = 0; i < 8; ++i)
      t8[i] = fmaxf(fmaxf(s0[i], s0[i + 8]), fmaxf(s1[i], s1[i + 8]));
    float t4a = fmaxf(t8[0], t8[4]), t4b = fmaxf(t8[1], t8[5]);
    float t4c = fmaxf(t8[2], t8[6]), t4d = fmaxf(t8[3], t8[7]);
    float mx = fmaxf(fmaxf(t4a, t4b), fmaxf(t4c, t4d));
    float pm = fmaxf(mx, __shfl_xor(mx, 32, 64));

    // defer-max rescale (log2 domain, THR = 8 -> P bounded by 256)
    float mnew = fmaxf(m_run, pm);
    if (!__all(pm <= m_run + 8.0f)) {
      float corr = __builtin_amdgcn_exp2f(m_run - mnew);
      lsum *= corr;
#pragma unroll
      for (int i = 0; i < 16; ++i) { o0[i] *= corr; o1[i] *= corr; }
      m_run = mnew;
    }

    // P = exp2(S - m)
#pragma unroll
    for (int i = 0; i < 16; ++i) {
      s0[i] = __builtin_amdgcn_exp2f(s0[i] - m_run);
      s1[i] = __builtin_amdgcn_exp2f(s1[i] - m_run);
    }
    // row sum (tree over own 32; partner half combined in epilogue)
    float u8[8];
#pragma unroll
    for (int i = 0; i < 8; ++i) u8[i] = (s0[i] + s0[i + 8]) + (s1[i] + s1[i + 8]);
    lsum += ((u8[0] + u8[4]) + (u8[1] + u8[5])) + ((u8[2] + u8[6]) + (u8[3] + u8[7]));

    // pack P frags: slice t holds 8 consecutive regs (kv = 16t + lane-owned set)
    bf16x8 pt[4];
    {
      union { unsigned int w[4]; bf16x8 v; } u;
      u.w[0] = pkbf(s0[0], s0[1]); u.w[1] = pkbf(s0[2], s0[3]);
      u.w[2] = pkbf(s0[4], s0[5]); u.w[3] = pkbf(s0[6], s0[7]);
      pt[0] = u.v;
      u.w[0] = pkbf(s0[8], s0[9]); u.w[1] = pkbf(s0[10], s0[11]);
      u.w[2] = pkbf(s0[12], s0[13]); u.w[3] = pkbf(s0[14], s0[15]);
      pt[1] = u.v;
      u.w[0] = pkbf(s1[0], s1[1]); u.w[1] = pkbf(s1[2], s1[3]);
      u.w[2] = pkbf(s1[4], s1[5]); u.w[3] = pkbf(s1[6], s1[7]);
      pt[2] = u.v;
      u.w[0] = pkbf(s1[8], s1[9]); u.w[1] = pkbf(s1[10], s1[11]);
      u.w[2] = pkbf(s1[12], s1[13]); u.w[3] = pkbf(s1[14], s1[15]);
      pt[3] = u.v;
    }

    // O^T += V^T . P^T  (A = V-frag, B = P-frag, identical chosen k-map)
#pragma unroll
    for (int t = 0; t < 4; ++t) {
      union { ushort4v h[2]; bf16x8 v; } va, vb;
      va.h[0] = vw[t][0]; va.h[1] = vw[t][1];
      vb.h[0] = vw[t][2]; vb.h[1] = vw[t][3];
      o0 = MFMA32(va.v, pt[t], o0);
      o1 = MFMA32(vb.v, pt[t], o1);
    }
  }

  // epilogue: combine partner halves of l, normalize, pack pairs, store dwords
  float ltot = lsum + __shfl_xor(lsum, 32, 64);
  float rinv = 1.0f / ltot;
  unsigned short* ob = Ob + (size_t)qrow * 512 + h * 64 + 4 * hi;
#pragma unroll
  for (int i = 0; i < 8; ++i) {
    int dvlo = ((2 * i) & 3) + 8 * ((2 * i) >> 2);
    *(unsigned int*)(ob + dvlo) = pkbf(o0[2 * i] * rinv, o0[2 * i + 1] * rinv);
    *(unsigned int*)(ob + 32 + dvlo) = pkbf(o1[2 * i] * rinv, o1[2 * i + 1] * rinv);
  }
}

// ---------------- launcher ----------------
extern "C" void kernel_launch(void* const* d_in, const int* in_sizes, int n_in,
                              void* d_out, int out_size, void* d_ws, size_t ws_size,
                              hipStream_t stream) {
  const float* x   = (const float*)d_in[0];
  const float* ctx = (const float*)d_in[1];
  const float* Wq  = (const float*)d_in[2];
  const float* Wkv = (const float*)d_in[3];
  const float* Wo  = (const float*)d_in[4];
  const float* bo  = (const float*)d_in[5];
  float* out = (float*)d_out;

  char* ws = (char*)d_ws;
  unsigned short* xt   = (unsigned short*)(ws + 0);
  unsigned short* ct   = (unsigned short*)(ws + 8388608);
  unsigned short* Wqt  = (unsigned short*)(ws + 16777216);
  unsigned short* Wkvt = (unsigned short*)(ws + 17301504);
  unsigned short* Wot  = (unsigned short*)(ws + 18350080);
  unsigned short* Qb   = (unsigned short*)(ws + 18874368);
  unsigned short* Kb   = (unsigned short*)(ws + 27262976);
  unsigned short* Vtb  = (unsigned short*)(ws + 35651584);
  unsigned short* Ob   = (unsigned short*)(ws + 44040192);

  transpose_cast_kernel<<<dim3(64, 16, 4), 256, 0, stream>>>(x, xt, 512, 2048);
  transpose_cast_kernel<<<dim3(64, 16, 4), 256, 0, stream>>>(ctx, ct, 512, 2048);
  transpose_cast_kernel<<<dim3(16, 16, 1), 256, 0, stream>>>(Wq, Wqt, 512, 512);
  transpose_cast_kernel<<<dim3(32, 16, 1), 256, 0, stream>>>(Wkv, Wkvt, 512, 1024);
  transpose_cast_kernel<<<dim3(16, 16, 1), 256, 0, stream>>>(Wo, Wot, 512, 512);

  gemm_q_kernel<<<dim3(64, 8), 256, 0, stream>>>(xt, Wqt, Qb);
  gemm_kv_kernel<<<dim3(64, 16), 256, 0, stream>>>(ct, Wkvt, Kb, Vtb);

  attn_kernel<<<dim3(16, 8, 4), 256, 0, stream>>>(Qb, Kb, Vtb, Ob);

  gemm_out_kernel<<<dim3(64, 8), 256, 0, stream>>>(Ob, Wot, out, bo);
}

// Round 4
// 121.250 us; speedup vs baseline: 1.9445x; 1.9445x over previous
//
#include <hip/hip_runtime.h>
#include <hip/hip_bf16.h>

typedef __attribute__((ext_vector_type(8))) short bf16x8;
typedef __attribute__((ext_vector_type(4))) float f32x4;
typedef __attribute__((ext_vector_type(16))) float f32x16;
typedef __attribute__((ext_vector_type(8))) unsigned short ushort8v;
typedef __attribute__((ext_vector_type(4))) unsigned short ushort4v;

#define MFMA16(a, b, c) __builtin_amdgcn_mfma_f32_16x16x32_bf16((a), (b), (c), 0, 0, 0)
#define MFMA32(a, b, c) __builtin_amdgcn_mfma_f32_32x32x16_bf16((a), (b), (c), 0, 0, 0)

__device__ __forceinline__ unsigned short f2bf(float f) {
  union { float f; unsigned int u; } v; v.f = f;
  unsigned int r = v.u + 0x7FFFu + ((v.u >> 16) & 1u);
  return (unsigned short)(r >> 16);
}

// packed f32 pair -> bf16 pair (lo = a, hi = b), RNE
__device__ __forceinline__ unsigned int pkbf(float a, float b) {
  float2 t; t.x = a; t.y = b;
  __hip_bfloat162 h = __float22bfloat162_rn(t);
  union { __hip_bfloat162 h; unsigned int w; } c; c.h = h;
  return c.w;
}

// ---------------- transpose + cast: in (R,C) f32 -> out (C,R) bf16, batched ----------------
__global__ __launch_bounds__(256) void transpose_cast_kernel(
    const float* __restrict__ in, unsigned short* __restrict__ out, int R, int C) {
  __shared__ float tile[32][33];
  int c0 = blockIdx.x * 32, r0 = blockIdx.y * 32, b = blockIdx.z;
  const float* inb = in + (size_t)b * R * C;
  unsigned short* outb = out + (size_t)b * R * C;
  int tx = threadIdx.x & 31, ty = threadIdx.x >> 5;
#pragma unroll
  for (int k = 0; k < 4; ++k)
    tile[ty + 8 * k][tx] = inb[(size_t)(r0 + ty + 8 * k) * C + c0 + tx];
  __syncthreads();
#pragma unroll
  for (int k = 0; k < 4; ++k)
    outb[(size_t)(c0 + ty + 8 * k) * R + r0 + tx] = f2bf(tile[tx][ty + 8 * k]);
}

// ---------------- shared NT-GEMM core ----------------
__device__ __forceinline__ void gemm_acc(
    const unsigned short* __restrict__ A, const unsigned short* __restrict__ Bt,
    int l0, int o0, f32x4 acc[4][2],
    unsigned short (*As)[80], unsigned short (*Bs)[80]) {
  int tid = threadIdx.x, lane = tid & 63, wave = tid >> 6;
  int wl = wave >> 1, wo = wave & 1, lg = lane >> 4, lr = lane & 15;
  for (int kb = 0; kb < 512; kb += 64) {
    {
      int row = tid >> 1, cc = (tid & 1) * 32;
      const ushort8v* src = (const ushort8v*)(A + (size_t)(l0 + row) * 512 + kb + cc);
#pragma unroll
      for (int i = 0; i < 4; ++i) *(ushort8v*)&As[row][cc + 8 * i] = src[i];
      int row2 = tid >> 2, c2 = (tid & 3) * 16;
      const ushort8v* srcb = (const ushort8v*)(Bt + (size_t)(o0 + row2) * 512 + kb + c2);
      *(ushort8v*)&Bs[row2][c2] = srcb[0];
      *(ushort8v*)&Bs[row2][c2 + 8] = srcb[1];
    }
    __syncthreads();
#pragma unroll
    for (int kc = 0; kc < 2; ++kc) {
      bf16x8 af[4], bfr[2];
#pragma unroll
      for (int mf = 0; mf < 4; ++mf)
        af[mf] = *(const bf16x8*)&As[wl * 64 + mf * 16 + lr][kc * 32 + 8 * lg];
#pragma unroll
      for (int nf = 0; nf < 2; ++nf)
        bfr[nf] = *(const bf16x8*)&Bs[wo * 32 + nf * 16 + lr][kc * 32 + 8 * lg];
#pragma unroll
      for (int mf = 0; mf < 4; ++mf)
#pragma unroll
        for (int nf = 0; nf < 2; ++nf)
          acc[mf][nf] = MFMA16(af[mf], bfr[nf], acc[mf][nf]);
    }
    __syncthreads();
  }
}

// Q projection: C (8192, 512) bf16, PRE-SCALED by dim_head^-0.5 * log2(e).
__global__ __launch_bounds__(256) void gemm_q_kernel(
    const unsigned short* __restrict__ A, const unsigned short* __restrict__ Bt,
    unsigned short* __restrict__ C) {
  __shared__ unsigned short As[128][80];
  __shared__ unsigned short Bs[64][80];
  f32x4 acc[4][2] = {};
  int l0 = blockIdx.x * 128, o0 = blockIdx.y * 64;
  gemm_acc(A, Bt, l0, o0, acc, As, Bs);
  int lane = threadIdx.x & 63, wave = threadIdx.x >> 6;
  int wl = wave >> 1, wo = wave & 1, lg = lane >> 4, lr = lane & 15;
  const float qs = 0.18033688011112042f;  // 0.125 * log2(e)
#pragma unroll
  for (int mf = 0; mf < 4; ++mf)
#pragma unroll
    for (int nf = 0; nf < 2; ++nf)
#pragma unroll
      for (int r = 0; r < 4; ++r) {
        int row = l0 + wl * 64 + mf * 16 + 4 * lg + r;
        int col = o0 + wo * 32 + nf * 16 + lr;
        C[(size_t)row * 512 + col] = f2bf(acc[mf][nf][r] * qs);
      }
}

// KV projection: cols [0,512) -> K (B*M, 512); cols [512,1024) -> Vt (B,H,64,M-permuted).
// V column index has bits 2<->3 swapped so attention's chosen PV k-map is 16B-contiguous.
__global__ __launch_bounds__(256) void gemm_kv_kernel(
    const unsigned short* __restrict__ A, const unsigned short* __restrict__ Bt,
    unsigned short* __restrict__ K, unsigned short* __restrict__ Vt) {
  __shared__ unsigned short As[128][80];
  __shared__ unsigned short Bs[64][80];
  f32x4 acc[4][2] = {};
  int l0 = blockIdx.x * 128, o0 = blockIdx.y * 64;
  gemm_acc(A, Bt, l0, o0, acc, As, Bs);
  int lane = threadIdx.x & 63, wave = threadIdx.x >> 6;
  int wl = wave >> 1, wo = wave & 1, lg = lane >> 4, lr = lane & 15;
  if (o0 < 512) {
#pragma unroll
    for (int mf = 0; mf < 4; ++mf)
#pragma unroll
      for (int nf = 0; nf < 2; ++nf)
#pragma unroll
        for (int r = 0; r < 4; ++r) {
          int row = l0 + wl * 64 + mf * 16 + 4 * lg + r;
          int col = o0 + wo * 32 + nf * 16 + lr;
          K[(size_t)row * 512 + col] = f2bf(acc[mf][nf][r]);
        }
  } else {
    int b = l0 >> 11;
#pragma unroll
    for (int mf = 0; mf < 4; ++mf)
#pragma unroll
      for (int nf = 0; nf < 2; ++nf) {
        int m0v = (l0 & 2047) + wl * 64 + mf * 16 + 4 * lg;
        int msw = (m0v & ~12) | ((m0v & 4) << 1) | ((m0v & 8) >> 1);  // swap bits 2,3
        int oh = (o0 - 512) + wo * 32 + nf * 16 + lr;
        int h = oh >> 6, d = oh & 63;
        ushort4v pk;
#pragma unroll
        for (int r = 0; r < 4; ++r) pk[r] = f2bf(acc[mf][nf][r]);
        *(ushort4v*)&Vt[(size_t)((b * 8 + h) * 64 + d) * 2048 + msw] = pk;
      }
  }
}

// Out projection: out (B, 512, N) fp32 transposed store + bias.
__global__ __launch_bounds__(256) void gemm_out_kernel(
    const unsigned short* __restrict__ A, const unsigned short* __restrict__ Bt,
    float* __restrict__ Out, const float* __restrict__ bias) {
  __shared__ unsigned short As[128][80];
  __shared__ unsigned short Bs[64][80];
  f32x4 acc[4][2] = {};
  int l0 = blockIdx.x * 128, o0 = blockIdx.y * 64;
  gemm_acc(A, Bt, l0, o0, acc, As, Bs);
  int lane = threadIdx.x & 63, wave = threadIdx.x >> 6;
  int wl = wave >> 1, wo = wave & 1, lg = lane >> 4, lr = lane & 15;
#pragma unroll
  for (int mf = 0; mf < 4; ++mf)
#pragma unroll
    for (int nf = 0; nf < 2; ++nf) {
      int row = l0 + wl * 64 + mf * 16 + 4 * lg;
      int col = o0 + wo * 32 + nf * 16 + lr;
      int b = row >> 11, n = row & 2047;
      float bv = bias[col];
      f32x4 v = acc[mf][nf];
#pragma unroll
      for (int r = 0; r < 4; ++r) v[r] += bv;
      *(f32x4*)&Out[((size_t)(b * 512 + col)) * 2048 + n] = v;
    }
}

// ---------------- flash attention: in-reg softmax + LDS-staged K/V ----------------
// grid (16, 8, 4); 4 waves x 32 q-rows; KV tile 64; D = 64.
// S^T = mfma32(K, Q); lane owns q = lane&31; s[r] = S^T[kv=(r&3)+8*(r>>2)+4*hi][q].
// K/V tiles staged to LDS [64][64] with XOR swizzle byte^=((row&7)<<4); coalesced,
// shared by 4 waves, double-buffered, issue-early/write-late reg staging.
// V global layout is kv-bit2<->3 swapped so PV fragments are 16B-contiguous.
__global__ __launch_bounds__(256) void attn_kernel(
    const unsigned short* __restrict__ Qb, const unsigned short* __restrict__ Kb,
    const unsigned short* __restrict__ Vt, unsigned short* __restrict__ Ob) {
  __shared__ unsigned short Ks[2][64][64];
  __shared__ unsigned short Vs[2][64][64];
  int h = blockIdx.y, b = blockIdx.z;
  int tid = threadIdx.x, wave = tid >> 6, lane = tid & 63;
  int l31 = lane & 31, hi = lane >> 5;
  int qrow = b * 2048 + blockIdx.x * 128 + wave * 32 + l31;

  // Q fragments (once)
  const unsigned short* qp = Qb + (size_t)qrow * 512 + h * 64 + 8 * hi;
  bf16x8 qf[4];
#pragma unroll
  for (int dk = 0; dk < 4; ++dk) qf[dk] = *(const bf16x8*)(qp + 16 * dk);

  // staging coords: thread covers rows rr and rr+8, one 16B chunk each
  int rr = (wave << 4) + (lane >> 3);
  int lc = lane & 7;                 // LDS chunk written
  int gc = lc ^ (rr & 7);            // global chunk read (pre-swizzled source)
  const unsigned short* kgbase =
      Kb + (size_t)(b * 2048 + rr) * 512 + h * 64 + gc * 8;
  const unsigned short* vgbase =
      Vt + (size_t)((b * 8 + h) * 64 + rr) * 2048 + gc * 8;

  f32x16 o0 = {}, o1 = {};
  float m_run = -1e30f, lsum = 0.0f;

  const char* ksbase = (const char*)&Ks[0][0][0];
  const char* vsbase = (const char*)&Vs[0][0][0];
  int swz = (l31 & 7) << 4;

  // prologue: stage tile 0 into buf 0
  {
    ushort8v ka = *(const ushort8v*)(kgbase);
    ushort8v ka2 = *(const ushort8v*)(kgbase + (size_t)8 * 512);
    ushort8v va = *(const ushort8v*)(vgbase);
    ushort8v va2 = *(const ushort8v*)(vgbase + (size_t)8 * 2048);
    *(ushort8v*)&Ks[0][rr][lc * 8] = ka;
    *(ushort8v*)&Ks[0][rr + 8][lc * 8] = ka2;
    *(ushort8v*)&Vs[0][rr][lc * 8] = va;
    *(ushort8v*)&Vs[0][rr + 8][lc * 8] = va2;
  }
  __syncthreads();

#pragma unroll 1
  for (int m0 = 0; m0 < 2048; m0 += 64) {
    int buf = (m0 >> 6) & 1;
    bool hasnext = (m0 + 64) < 2048;
    ushort8v ka, ka2, va, va2;
    if (hasnext) {  // issue next-tile loads early; land during compute
      ka = *(const ushort8v*)(kgbase + (size_t)(m0 + 64) * 512);
      ka2 = *(const ushort8v*)(kgbase + (size_t)(m0 + 72) * 512);
      va = *(const ushort8v*)(vgbase + m0 + 64);
      va2 = *(const ushort8v*)(vgbase + (size_t)8 * 2048 + m0 + 64);
    }

    const char* kb = ksbase + (size_t)buf * 8192;
    const char* vb = vsbase + (size_t)buf * 8192;

    // S^T for two 32-kv subtiles (K frags from swizzled LDS)
    f32x16 s0 = {}, s1 = {};
#pragma unroll
    for (int dk = 0; dk < 4; ++dk) {
      bf16x8 k0 = *(const bf16x8*)(kb + l31 * 128 + ((dk * 32 + 16 * hi) ^ swz));
      s0 = MFMA32(k0, qf[dk], s0);
    }
#pragma unroll
    for (int dk = 0; dk < 4; ++dk) {
      bf16x8 k1 = *(const bf16x8*)(kb + (32 + l31) * 128 + ((dk * 32 + 16 * hi) ^ swz));
      s1 = MFMA32(k1, qf[dk], s1);
    }

    // V frags (chosen k-map, 16B contiguous in permuted layout)
    bf16x8 vfa[4], vfb[4];
#pragma unroll
    for (int t = 0; t < 4; ++t) {
      vfa[t] = *(const bf16x8*)(vb + l31 * 128 + ((t * 32 + 16 * hi) ^ swz));
      vfb[t] = *(const bf16x8*)(vb + (32 + l31) * 128 + ((t * 32 + 16 * hi) ^ swz));
    }

    // row max over this lane's 32 scores, partner (lane^32) combine
    float t8[8];
#pragma unroll
    for (int i = 0; i < 8; ++i)
      t8[i] = fmaxf(fmaxf(s0[i], s0[i + 8]), fmaxf(s1[i], s1[i + 8]));
    float t4a = fmaxf(t8[0], t8[4]), t4b = fmaxf(t8[1], t8[5]);
    float t4c = fmaxf(t8[2], t8[6]), t4d = fmaxf(t8[3], t8[7]);
    float mx = fmaxf(fmaxf(t4a, t4b), fmaxf(t4c, t4d));
    float pm = fmaxf(mx, __shfl_xor(mx, 32, 64));

    // defer-max rescale (log2 domain, THR = 8 -> P bounded by 256)
    float mnew = fmaxf(m_run, pm);
    if (!__all(pm <= m_run + 8.0f)) {
      float corr = __builtin_amdgcn_exp2f(m_run - mnew);
      lsum *= corr;
#pragma unroll
      for (int i = 0; i < 16; ++i) { o0[i] *= corr; o1[i] *= corr; }
      m_run = mnew;
    }

    // P = exp2(S - m)
#pragma unroll
    for (int i = 0; i < 16; ++i) {
      s0[i] = __builtin_amdgcn_exp2f(s0[i] - m_run);
      s1[i] = __builtin_amdgcn_exp2f(s1[i] - m_run);
    }
    // row sum (tree; partner half combined in epilogue)
    float u8[8];
#pragma unroll
    for (int i = 0; i < 8; ++i) u8[i] = (s0[i] + s0[i + 8]) + (s1[i] + s1[i + 8]);
    lsum += ((u8[0] + u8[4]) + (u8[1] + u8[5])) + ((u8[2] + u8[6]) + (u8[3] + u8[7]));

    // pack P frags (lane-local, no cross-lane)
    bf16x8 pt[4];
    {
      union { unsigned int w[4]; bf16x8 v; } u;
      u.w[0] = pkbf(s0[0], s0[1]); u.w[1] = pkbf(s0[2], s0[3]);
      u.w[2] = pkbf(s0[4], s0[5]); u.w[3] = pkbf(s0[6], s0[7]);
      pt[0] = u.v;
      u.w[0] = pkbf(s0[8], s0[9]); u.w[1] = pkbf(s0[10], s0[11]);
      u.w[2] = pkbf(s0[12], s0[13]); u.w[3] = pkbf(s0[14], s0[15]);
      pt[1] = u.v;
      u.w[0] = pkbf(s1[0], s1[1]); u.w[1] = pkbf(s1[2], s1[3]);
      u.w[2] = pkbf(s1[4], s1[5]); u.w[3] = pkbf(s1[6], s1[7]);
      pt[2] = u.v;
      u.w[0] = pkbf(s1[8], s1[9]); u.w[1] = pkbf(s1[10], s1[11]);
      u.w[2] = pkbf(s1[12], s1[13]); u.w[3] = pkbf(s1[14], s1[15]);
      pt[3] = u.v;
    }

    // O^T += V^T . P^T
#pragma unroll
    for (int t = 0; t < 4; ++t) {
      o0 = MFMA32(vfa[t], pt[t], o0);
      o1 = MFMA32(vfb[t], pt[t], o1);
    }

    // publish next tile (write-late; compiler waits vmcnt before use)
    if (hasnext) {
      int nb = buf ^ 1;
      *(ushort8v*)&Ks[nb][rr][lc * 8] = ka;
      *(ushort8v*)&Ks[nb][rr + 8][lc * 8] = ka2;
      *(ushort8v*)&Vs[nb][rr][lc * 8] = va;
      *(ushort8v*)&Vs[nb][rr + 8][lc * 8] = va2;
    }
    __syncthreads();
  }

  // epilogue: combine partner halves of l, normalize, pack pairs, store dwords
  float ltot = lsum + __shfl_xor(lsum, 32, 64);
  float rinv = 1.0f / ltot;
  unsigned short* ob = Ob + (size_t)qrow * 512 + h * 64 + 4 * hi;
#pragma unroll
  for (int i = 0; i < 8; ++i) {
    int dvlo = ((2 * i) & 3) + 8 * ((2 * i) >> 2);
    *(unsigned int*)(ob + dvlo) = pkbf(o0[2 * i] * rinv, o0[2 * i + 1] * rinv);
    *(unsigned int*)(ob + 32 + dvlo) = pkbf(o1[2 * i] * rinv, o1[2 * i + 1] * rinv);
  }
}

// ---------------- launcher ----------------
extern "C" void kernel_launch(void* const* d_in, const int* in_sizes, int n_in,
                              void* d_out, int out_size, void* d_ws, size_t ws_size,
                              hipStream_t stream) {
  const float* x   = (const float*)d_in[0];
  const float* ctx = (const float*)d_in[1];
  const float* Wq  = (const float*)d_in[2];
  const float* Wkv = (const float*)d_in[3];
  const float* Wo  = (const float*)d_in[4];
  const float* bo  = (const float*)d_in[5];
  float* out = (float*)d_out;

  char* ws = (char*)d_ws;
  unsigned short* xt   = (unsigned short*)(ws + 0);
  unsigned short* ct   = (unsigned short*)(ws + 8388608);
  unsigned short* Wqt  = (unsigned short*)(ws + 16777216);
  unsigned short* Wkvt = (unsigned short*)(ws + 17301504);
  unsigned short* Wot  = (unsigned short*)(ws + 18350080);
  unsigned short* Qb   = (unsigned short*)(ws + 18874368);
  unsigned short* Kb   = (unsigned short*)(ws + 27262976);
  unsigned short* Vtb  = (unsigned short*)(ws + 35651584);
  unsigned short* Ob   = (unsigned short*)(ws + 44040192);

  transpose_cast_kernel<<<dim3(64, 16, 4), 256, 0, stream>>>(x, xt, 512, 2048);
  transpose_cast_kernel<<<dim3(64, 16, 4), 256, 0, stream>>>(ctx, ct, 512, 2048);
  transpose_cast_kernel<<<dim3(16, 16, 1), 256, 0, stream>>>(Wq, Wqt, 512, 512);
  transpose_cast_kernel<<<dim3(32, 16, 1), 256, 0, stream>>>(Wkv, Wkvt, 512, 1024);
  transpose_cast_kernel<<<dim3(16, 16, 1), 256, 0, stream>>>(Wo, Wot, 512, 512);

  gemm_q_kernel<<<dim3(64, 8), 256, 0, stream>>>(xt, Wqt, Qb);
  gemm_kv_kernel<<<dim3(64, 16), 256, 0, stream>>>(ct, Wkvt, Kb, Vtb);

  attn_kernel<<<dim3(16, 8, 4), 256, 0, stream>>>(Qb, Kb, Vtb, Ob);

  gemm_out_kernel<<<dim3(64, 8), 256, 0, stream>>>(Ob, Wot, out, bo);
}

// Round 5
// 119.847 us; speedup vs baseline: 1.9673x; 1.0117x over previous
//
#include <hip/hip_runtime.h>
#include <hip/hip_bf16.h>

typedef __attribute__((ext_vector_type(8))) short bf16x8;
typedef __attribute__((ext_vector_type(4))) float f32x4;
typedef __attribute__((ext_vector_type(16))) float f32x16;
typedef __attribute__((ext_vector_type(8))) unsigned short ushort8v;
typedef __attribute__((ext_vector_type(4))) unsigned short ushort4v;

#define MFMA16(a, b, c) __builtin_amdgcn_mfma_f32_16x16x32_bf16((a), (b), (c), 0, 0, 0)
#define MFMA32(a, b, c) __builtin_amdgcn_mfma_f32_32x32x16_bf16((a), (b), (c), 0, 0, 0)

__device__ __forceinline__ unsigned short f2bf(float f) {
  union { float f; unsigned int u; } v; v.f = f;
  unsigned int r = v.u + 0x7FFFu + ((v.u >> 16) & 1u);
  return (unsigned short)(r >> 16);
}

__device__ __forceinline__ unsigned int pkbf(float a, float b) {
  float2 t; t.x = a; t.y = b;
  __hip_bfloat162 h = __float22bfloat162_rn(t);
  union { __hip_bfloat162 h; unsigned int w; } c; c.h = h;
  return c.w;
}

// ---------------- transpose + cast: in (R,C) f32 -> out (C,R) bf16, batched ----------------
__global__ __launch_bounds__(256) void transpose_cast_kernel(
    const float* __restrict__ in, unsigned short* __restrict__ out, int R, int C) {
  __shared__ float tile[32][33];
  int c0 = blockIdx.x * 32, r0 = blockIdx.y * 32, b = blockIdx.z;
  const float* inb = in + (size_t)b * R * C;
  unsigned short* outb = out + (size_t)b * R * C;
  int tx = threadIdx.x & 31, ty = threadIdx.x >> 5;
#pragma unroll
  for (int k = 0; k < 4; ++k)
    tile[ty + 8 * k][tx] = inb[(size_t)(r0 + ty + 8 * k) * C + c0 + tx];
  __syncthreads();
#pragma unroll
  for (int k = 0; k < 4; ++k)
    outb[(size_t)(c0 + ty + 8 * k) * R + r0 + tx] = f2bf(tile[tx][ty + 8 * k]);
}

// ---------------- shared NT-GEMM core, 128x128 tile ----------------
// C[l][o] = sum_d A[l][d]*Bt[o][d], K=512, BK=64; 4 waves 2x2, wave tile 64x64.
__device__ __forceinline__ void gemm_acc128(
    const unsigned short* __restrict__ A, const unsigned short* __restrict__ Bt,
    int l0, int o0, f32x4 acc[4][4],
    unsigned short (*As)[80], unsigned short (*Bs)[80]) {
  int tid = threadIdx.x, lane = tid & 63, wave = tid >> 6;
  int wl = wave >> 1, wo = wave & 1, lg = lane >> 4, lr = lane & 15;
  for (int kb = 0; kb < 512; kb += 64) {
    {
      int row = tid >> 1, cc = (tid & 1) * 32;
      const ushort8v* srca = (const ushort8v*)(A + (size_t)(l0 + row) * 512 + kb + cc);
      const ushort8v* srcb = (const ushort8v*)(Bt + (size_t)(o0 + row) * 512 + kb + cc);
#pragma unroll
      for (int i = 0; i < 4; ++i) *(ushort8v*)&As[row][cc + 8 * i] = srca[i];
#pragma unroll
      for (int i = 0; i < 4; ++i) *(ushort8v*)&Bs[row][cc + 8 * i] = srcb[i];
    }
    __syncthreads();
#pragma unroll
    for (int kc = 0; kc < 2; ++kc) {
      bf16x8 af[4], bfr[4];
#pragma unroll
      for (int mf = 0; mf < 4; ++mf)
        af[mf] = *(const bf16x8*)&As[wl * 64 + mf * 16 + lr][kc * 32 + 8 * lg];
#pragma unroll
      for (int nf = 0; nf < 4; ++nf)
        bfr[nf] = *(const bf16x8*)&Bs[wo * 64 + nf * 16 + lr][kc * 32 + 8 * lg];
#pragma unroll
      for (int mf = 0; mf < 4; ++mf)
#pragma unroll
        for (int nf = 0; nf < 4; ++nf)
          acc[mf][nf] = MFMA16(af[mf], bfr[nf], acc[mf][nf]);
    }
    __syncthreads();
  }
}

// Q projection: C (8192,512) bf16, PRE-SCALED by dim_head^-0.5 * log2(e).
__global__ __launch_bounds__(256) void gemm_q_kernel(
    const unsigned short* __restrict__ A, const unsigned short* __restrict__ Bt,
    unsigned short* __restrict__ C) {
  __shared__ unsigned short As[128][80];
  __shared__ unsigned short Bs[128][80];
  f32x4 acc[4][4] = {};
  int l0 = blockIdx.x * 128, o0 = blockIdx.y * 128;
  gemm_acc128(A, Bt, l0, o0, acc, As, Bs);
  int lane = threadIdx.x & 63, wave = threadIdx.x >> 6;
  int wl = wave >> 1, wo = wave & 1, lg = lane >> 4, lr = lane & 15;
  const float qs = 0.18033688011112042f;  // 0.125 * log2(e)
#pragma unroll
  for (int mf = 0; mf < 4; ++mf)
#pragma unroll
    for (int nf = 0; nf < 4; ++nf)
#pragma unroll
      for (int r = 0; r < 4; ++r) {
        int row = l0 + wl * 64 + mf * 16 + 4 * lg + r;
        int col = o0 + wo * 64 + nf * 16 + lr;
        C[(size_t)row * 512 + col] = f2bf(acc[mf][nf][r] * qs);
      }
}

// KV projection: cols [0,512) -> K (B*M,512); cols [512,1024) -> Vt (B,H,64,M-permuted).
// V kv-index has bits 2<->3 swapped so attention's chosen PV k-map is 16B-contiguous.
__global__ __launch_bounds__(256) void gemm_kv_kernel(
    const unsigned short* __restrict__ A, const unsigned short* __restrict__ Bt,
    unsigned short* __restrict__ K, unsigned short* __restrict__ Vt) {
  __shared__ unsigned short As[128][80];
  __shared__ unsigned short Bs[128][80];
  f32x4 acc[4][4] = {};
  int l0 = blockIdx.x * 128, o0 = blockIdx.y * 128;
  gemm_acc128(A, Bt, l0, o0, acc, As, Bs);
  int lane = threadIdx.x & 63, wave = threadIdx.x >> 6;
  int wl = wave >> 1, wo = wave & 1, lg = lane >> 4, lr = lane & 15;
  if (o0 < 512) {
#pragma unroll
    for (int mf = 0; mf < 4; ++mf)
#pragma unroll
      for (int nf = 0; nf < 4; ++nf)
#pragma unroll
        for (int r = 0; r < 4; ++r) {
          int row = l0 + wl * 64 + mf * 16 + 4 * lg + r;
          int col = o0 + wo * 64 + nf * 16 + lr;
          K[(size_t)row * 512 + col] = f2bf(acc[mf][nf][r]);
        }
  } else {
    int b = l0 >> 11;
#pragma unroll
    for (int mf = 0; mf < 4; ++mf)
#pragma unroll
      for (int nf = 0; nf < 4; ++nf) {
        int m0v = (l0 & 2047) + wl * 64 + mf * 16 + 4 * lg;
        int msw = (m0v & ~12) | ((m0v & 4) << 1) | ((m0v & 8) >> 1);  // swap bits 2,3
        int oh = (o0 - 512) + wo * 64 + nf * 16 + lr;
        int h = oh >> 6, d = oh & 63;
        ushort4v pk;
#pragma unroll
        for (int r = 0; r < 4; ++r) pk[r] = f2bf(acc[mf][nf][r]);
        *(ushort4v*)&Vt[(size_t)((b * 8 + h) * 64 + d) * 2048 + msw] = pk;
      }
  }
}

// Out projection: out (B,512,N) fp32 transposed store + bias.
__global__ __launch_bounds__(256) void gemm_out_kernel(
    const unsigned short* __restrict__ A, const unsigned short* __restrict__ Bt,
    float* __restrict__ Out, const float* __restrict__ bias) {
  __shared__ unsigned short As[128][80];
  __shared__ unsigned short Bs[128][80];
  f32x4 acc[4][4] = {};
  int l0 = blockIdx.x * 128, o0 = blockIdx.y * 128;
  gemm_acc128(A, Bt, l0, o0, acc, As, Bs);
  int lane = threadIdx.x & 63, wave = threadIdx.x >> 6;
  int wl = wave >> 1, wo = wave & 1, lg = lane >> 4, lr = lane & 15;
#pragma unroll
  for (int mf = 0; mf < 4; ++mf)
#pragma unroll
    for (int nf = 0; nf < 4; ++nf) {
      int row = l0 + wl * 64 + mf * 16 + 4 * lg;
      int col = o0 + wo * 64 + nf * 16 + lr;
      int b = row >> 11, n = row & 2047;
      float bv = bias[col];
      f32x4 v = acc[mf][nf];
#pragma unroll
      for (int r = 0; r < 4; ++r) v[r] += bv;
      *(f32x4*)&Out[((size_t)(b * 512 + col)) * 2048 + n] = v;
    }
}

// ---------------- flash attention R5 ----------------
// 1024 blocks x 128 threads. Block: 64 q-rows; 2 waves split kv (1024 each), LDS-merge.
// Per wave: 16 tiles of 64 kv; private single-buffer K/V in LDS via global_load_lds
// (linear dest, pre-swizzled global source, XOR read); NO barriers in main loop.
// S^T = mfma32(K, Q); lane owns q=lane&31; chosen PV k-map => lane-local P pack.
__device__ __forceinline__ void softmax_step(
    f32x16& s0, f32x16& s1, float& m_run, float& lsum,
    f32x16& oa, f32x16& ob, bf16x8 pt[4]) {
  float t8[8];
#pragma unroll
  for (int i = 0; i < 8; ++i)
    t8[i] = fmaxf(fmaxf(s0[i], s0[i + 8]), fmaxf(s1[i], s1[i + 8]));
  float t4a = fmaxf(t8[0], t8[4]), t4b = fmaxf(t8[1], t8[5]);
  float t4c = fmaxf(t8[2], t8[6]), t4d = fmaxf(t8[3], t8[7]);
  float mx = fmaxf(fmaxf(t4a, t4b), fmaxf(t4c, t4d));
  float pm = fmaxf(mx, __shfl_xor(mx, 32, 64));
  float mnew = fmaxf(m_run, pm);
  if (!__all(pm <= m_run + 8.0f)) {
    float corr = __builtin_amdgcn_exp2f(m_run - mnew);
    lsum *= corr;
#pragma unroll
    for (int i = 0; i < 16; ++i) { oa[i] *= corr; ob[i] *= corr; }
    m_run = mnew;
  }
#pragma unroll
  for (int i = 0; i < 16; ++i) {
    s0[i] = __builtin_amdgcn_exp2f(s0[i] - m_run);
    s1[i] = __builtin_amdgcn_exp2f(s1[i] - m_run);
  }
  float u8[8];
#pragma unroll
  for (int i = 0; i < 8; ++i) u8[i] = (s0[i] + s0[i + 8]) + (s1[i] + s1[i + 8]);
  lsum += ((u8[0] + u8[4]) + (u8[1] + u8[5])) + ((u8[2] + u8[6]) + (u8[3] + u8[7]));
  union { unsigned int w[4]; bf16x8 v; } u;
  u.w[0] = pkbf(s0[0], s0[1]); u.w[1] = pkbf(s0[2], s0[3]);
  u.w[2] = pkbf(s0[4], s0[5]); u.w[3] = pkbf(s0[6], s0[7]);
  pt[0] = u.v;
  u.w[0] = pkbf(s0[8], s0[9]); u.w[1] = pkbf(s0[10], s0[11]);
  u.w[2] = pkbf(s0[12], s0[13]); u.w[3] = pkbf(s0[14], s0[15]);
  pt[1] = u.v;
  u.w[0] = pkbf(s1[0], s1[1]); u.w[1] = pkbf(s1[2], s1[3]);
  u.w[2] = pkbf(s1[4], s1[5]); u.w[3] = pkbf(s1[6], s1[7]);
  pt[2] = u.v;
  u.w[0] = pkbf(s1[8], s1[9]); u.w[1] = pkbf(s1[10], s1[11]);
  u.w[2] = pkbf(s1[12], s1[13]); u.w[3] = pkbf(s1[14], s1[15]);
  pt[3] = u.v;
}

__global__ __launch_bounds__(128, 2) void attn_kernel(
    const unsigned short* __restrict__ Qb, const unsigned short* __restrict__ Kb,
    const unsigned short* __restrict__ Vt, unsigned short* __restrict__ Ob) {
  __shared__ unsigned short KV[2][8192];  // per wave: K tile 4096 elems | V tile 4096 elems
  __shared__ float ML[256];               // wave1 m/l per lane
  int id = blockIdx.x;
  int slot = id & 7, qb = (id >> 3) & 31, hbhi = id >> 8;
  int hb = hbhi * 8 + slot;  // (b*8+h); all 32 q-blocks of a head stay on one XCD
  int h = hb & 7, b = hb >> 3;
  int tid = threadIdx.x, wave = tid >> 6, lane = tid & 63;
  int l31 = lane & 31, hi = lane >> 5;
  int qrow0 = b * 2048 + qb * 64;

  // Q fragments, both q-groups (rows qrow0+l31, qrow0+32+l31)
  const unsigned short* qp = Qb + (size_t)(qrow0 + l31) * 512 + h * 64 + 8 * hi;
  bf16x8 qf0[4], qf1[4];
#pragma unroll
  for (int dk = 0; dk < 4; ++dk) {
    qf0[dk] = *(const bf16x8*)(qp + 16 * dk);
    qf1[dk] = *(const bf16x8*)(qp + (size_t)32 * 512 + 16 * dk);
  }

  // staging: per-lane pre-swizzled global source, linear LDS dest (lane*16B)
  int r8 = lane >> 3;
  int gc = (lane & 7) ^ r8;
  const unsigned short* kg = Kb + (size_t)(b * 2048 + r8) * 512 + h * 64 + gc * 8;
  const unsigned short* vg = Vt + (size_t)((b * 8 + h) * 64 + r8) * 2048 + gc * 8;
  unsigned short* myK = &KV[wave][0];
  unsigned short* myV = &KV[wave][4096];
  int kv0 = wave * 1024;

#define STAGE_K(mm)                                                              \
  _Pragma("unroll") for (int j = 0; j < 8; ++j)                                  \
      __builtin_amdgcn_global_load_lds(                                          \
          (const __attribute__((address_space(1))) void*)(kg + (size_t)((mm) + j * 8) * 512), \
          (__attribute__((address_space(3))) void*)(myK + j * 512), 16, 0, 0);
#define STAGE_V(mm)                                                              \
  _Pragma("unroll") for (int j = 0; j < 8; ++j)                                  \
      __builtin_amdgcn_global_load_lds(                                          \
          (const __attribute__((address_space(1))) void*)(vg + (size_t)(j * 8) * 2048 + (mm)), \
          (__attribute__((address_space(3))) void*)(myV + j * 512), 16, 0, 0);

  STAGE_K(kv0);
  STAGE_V(kv0);

  const char* kbC = (const char*)myK;
  const char* vbC = (const char*)myV;
  int swz = (l31 & 7) << 4;

  f32x16 o00 = {}, o01 = {}, o10 = {}, o11 = {};
  float m0r = -1e30f, m1r = -1e30f, ls0 = 0.0f, ls1 = 0.0f;

#pragma unroll 1
  for (int t = 0; t < 16; ++t) {
    asm volatile("s_waitcnt vmcnt(0)" ::: "memory");  // staged tile ready
    // K fragments (8 x ds_read_b128)
    bf16x8 kfr[8];
#pragma unroll
    for (int dk = 0; dk < 4; ++dk) {
      kfr[dk] = *(const bf16x8*)(kbC + l31 * 128 + ((dk * 32 + 16 * hi) ^ swz));
      kfr[4 + dk] = *(const bf16x8*)(kbC + (32 + l31) * 128 + ((dk * 32 + 16 * hi) ^ swz));
    }
    asm volatile("s_waitcnt lgkmcnt(0)" ::: "memory");  // K frags in regs
    if (t < 15) { STAGE_K(kv0 + (t + 1) * 64); }        // overwrite K buffer

    // QK^T for both q-groups
    f32x16 s00 = {}, s01 = {}, s10 = {}, s11 = {};
#pragma unroll
    for (int dk = 0; dk < 4; ++dk) {
      s00 = MFMA32(kfr[dk], qf0[dk], s00);
      s10 = MFMA32(kfr[dk], qf1[dk], s10);
      s01 = MFMA32(kfr[4 + dk], qf0[dk], s01);
      s11 = MFMA32(kfr[4 + dk], qf1[dk], s11);
    }

    // V fragments
    bf16x8 vfa[4], vfb[4];
#pragma unroll
    for (int q = 0; q < 4; ++q) {
      vfa[q] = *(const bf16x8*)(vbC + l31 * 128 + ((q * 32 + 16 * hi) ^ swz));
      vfb[q] = *(const bf16x8*)(vbC + (32 + l31) * 128 + ((q * 32 + 16 * hi) ^ swz));
    }
    asm volatile("s_waitcnt lgkmcnt(0)" ::: "memory");  // V frags in regs
    if (t < 15) { STAGE_V(kv0 + (t + 1) * 64); }        // overwrite V buffer

    // softmax + P-pack per group
    bf16x8 pt0[4], pt1[4];
    softmax_step(s00, s01, m0r, ls0, o00, o01, pt0);
    softmax_step(s10, s11, m1r, ls1, o10, o11, pt1);

    // O^T += V^T . P^T
#pragma unroll
    for (int q = 0; q < 4; ++q) {
      o00 = MFMA32(vfa[q], pt0[q], o00);
      o01 = MFMA32(vfb[q], pt0[q], o01);
      o10 = MFMA32(vfa[q], pt1[q], o10);
      o11 = MFMA32(vfb[q], pt1[q], o11);
    }
  }
#undef STAGE_K
#undef STAGE_V

  // per-wave row totals (both halves of the lane pair hold the row value)
  float lt0 = ls0 + __shfl_xor(ls0, 32, 64);
  float lt1 = ls1 + __shfl_xor(ls1, 32, 64);

  // merge the two kv-halves
  if (wave == 1) {
    float* mo = (float*)&KV[1][0];  // wave1's own staging region (16 KB)
#pragma unroll
    for (int i = 0; i < 16; ++i) {
      mo[lane * 64 + i] = o00[i];
      mo[lane * 64 + 16 + i] = o01[i];
      mo[lane * 64 + 32 + i] = o10[i];
      mo[lane * 64 + 48 + i] = o11[i];
    }
    ML[lane * 4 + 0] = m0r; ML[lane * 4 + 1] = lt0;
    ML[lane * 4 + 2] = m1r; ML[lane * 4 + 3] = lt1;
  }
  __syncthreads();
  if (wave == 0) {
    const float* mo = (const float*)&KV[1][0];
    float m0b = ML[lane * 4 + 0], l0b = ML[lane * 4 + 1];
    float m1b = ML[lane * 4 + 2], l1b = ML[lane * 4 + 3];
    float M0 = fmaxf(m0r, m0b);
    float c0a = __builtin_amdgcn_exp2f(m0r - M0), c0b = __builtin_amdgcn_exp2f(m0b - M0);
    float r0 = 1.0f / (lt0 * c0a + l0b * c0b);
    float M1 = fmaxf(m1r, m1b);
    float c1a = __builtin_amdgcn_exp2f(m1r - M1), c1b = __builtin_amdgcn_exp2f(m1b - M1);
    float r1 = 1.0f / (lt1 * c1a + l1b * c1b);

    unsigned short* ob0 = Ob + (size_t)(qrow0 + l31) * 512 + h * 64 + 4 * hi;
    unsigned short* ob1 = Ob + (size_t)(qrow0 + 32 + l31) * 512 + h * 64 + 4 * hi;
#pragma unroll
    for (int i = 0; i < 8; ++i) {
      int dvlo = ((2 * i) & 3) + 8 * ((2 * i) >> 2);
      float a0 = (o00[2 * i] * c0a + mo[lane * 64 + 2 * i] * c0b) * r0;
      float a1 = (o00[2 * i + 1] * c0a + mo[lane * 64 + 2 * i + 1] * c0b) * r0;
      *(unsigned int*)(ob0 + dvlo) = pkbf(a0, a1);
      float b0v = (o01[2 * i] * c0a + mo[lane * 64 + 16 + 2 * i] * c0b) * r0;
      float b1v = (o01[2 * i + 1] * c0a + mo[lane * 64 + 16 + 2 * i + 1] * c0b) * r0;
      *(unsigned int*)(ob0 + 32 + dvlo) = pkbf(b0v, b1v);
      float g0 = (o10[2 * i] * c1a + mo[lane * 64 + 32 + 2 * i] * c1b) * r1;
      float g1 = (o10[2 * i + 1] * c1a + mo[lane * 64 + 32 + 2 * i + 1] * c1b) * r1;
      *(unsigned int*)(ob1 + dvlo) = pkbf(g0, g1);
      float h0 = (o11[2 * i] * c1a + mo[lane * 64 + 48 + 2 * i] * c1b) * r1;
      float h1 = (o11[2 * i + 1] * c1a + mo[lane * 64 + 48 + 2 * i + 1] * c1b) * r1;
      *(unsigned int*)(ob1 + 32 + dvlo) = pkbf(h0, h1);
    }
  }
}

// ---------------- launcher ----------------
extern "C" void kernel_launch(void* const* d_in, const int* in_sizes, int n_in,
                              void* d_out, int out_size, void* d_ws, size_t ws_size,
                              hipStream_t stream) {
  const float* x   = (const float*)d_in[0];
  const float* ctx = (const float*)d_in[1];
  const float* Wq  = (const float*)d_in[2];
  const float* Wkv = (const float*)d_in[3];
  const float* Wo  = (const float*)d_in[4];
  const float* bo  = (const float*)d_in[5];
  float* out = (float*)d_out;

  char* ws = (char*)d_ws;
  unsigned short* xt   = (unsigned short*)(ws + 0);
  unsigned short* ct   = (unsigned short*)(ws + 8388608);
  unsigned short* Wqt  = (unsigned short*)(ws + 16777216);
  unsigned short* Wkvt = (unsigned short*)(ws + 17301504);
  unsigned short* Wot  = (unsigned short*)(ws + 18350080);
  unsigned short* Qb   = (unsigned short*)(ws + 18874368);
  unsigned short* Kb   = (unsigned short*)(ws + 27262976);
  unsigned short* Vtb  = (unsigned short*)(ws + 35651584);
  unsigned short* Ob   = (unsigned short*)(ws + 44040192);

  transpose_cast_kernel<<<dim3(64, 16, 4), 256, 0, stream>>>(x, xt, 512, 2048);
  transpose_cast_kernel<<<dim3(64, 16, 4), 256, 0, stream>>>(ctx, ct, 512, 2048);
  transpose_cast_kernel<<<dim3(16, 16, 1), 256, 0, stream>>>(Wq, Wqt, 512, 512);
  transpose_cast_kernel<<<dim3(32, 16, 1), 256, 0, stream>>>(Wkv, Wkvt, 512, 1024);
  transpose_cast_kernel<<<dim3(16, 16, 1), 256, 0, stream>>>(Wo, Wot, 512, 512);

  gemm_q_kernel<<<dim3(64, 4), 256, 0, stream>>>(xt, Wqt, Qb);
  gemm_kv_kernel<<<dim3(64, 8), 256, 0, stream>>>(ct, Wkvt, Kb, Vtb);

  attn_kernel<<<dim3(1024), 128, 0, stream>>>(Qb, Kb, Vtb, Ob);

  gemm_out_kernel<<<dim3(64, 4), 256, 0, stream>>>(Ob, Wot, out, bo);
}